// Round 10
// baseline (136.435 us; speedup 1.0000x reference)
//
#include <hip/hip_runtime.h>
#include <math.h>

// Problem constants
#define S_N 16
#define D_N 256
#define H_N 128
#define K_N 32
#define BT  64      // batch rows per workgroup
#define B_N 16384

typedef __attribute__((ext_vector_type(8))) short bf16x8;
typedef __attribute__((ext_vector_type(4))) float f32x4;
typedef __attribute__((ext_vector_type(16))) float f32x16;

#define MFMA16(a, b, c) __builtin_amdgcn_mfma_f32_16x16x32_bf16(a, b, c, 0, 0, 0)
#define MFMA32(a, b, c) __builtin_amdgcn_mfma_f32_32x32x16_bf16(a, b, c, 0, 0, 0)
// 16-row XOR swizzle: 32-row-span b128 reads stay <=2-way bank-aliased
#define SWZ(r) ((unsigned)(((r) & 15) << 4))

static __device__ __forceinline__ unsigned short f2bf(float f) {
  union { float f; unsigned u; } v; v.f = f;
  unsigned r = v.u + 0x7FFFu + ((v.u >> 16) & 1u);  // RNE
  return (unsigned short)(r >> 16);
}

// ---------------- merged pre-pass (unchanged layouts) ----------------
__global__ __launch_bounds__(256)
void lsi_prep(const float* __restrict__ W1, const float* __restrict__ W2,
              const float* __restrict__ Wc1, const float* __restrict__ b2,
              const float* __restrict__ bc1,
              unsigned short* __restrict__ W1t,
              unsigned short* __restrict__ W2t,
              unsigned short* __restrict__ Wft,
              float* __restrict__ bcf)
{
  const int bid = blockIdx.x;
  if (bid < 1024) {
    __shared__ float t[32][33];
    const float* src; unsigned short* dst; int R, C, r0, c0;
    if (bid < 512) {
      int s = bid >> 5, tt = bid & 31;
      R = 256; C = 128; r0 = (tt >> 2) * 32; c0 = (tt & 3) * 32;
      src = W1 + (size_t)s * 256 * 128; dst = W1t + (size_t)s * 128 * 256;
    } else {
      int s = (bid - 512) >> 5, tt = (bid - 512) & 31;
      R = 128; C = 256; r0 = (tt >> 3) * 32; c0 = (tt & 7) * 32;
      src = W2 + (size_t)s * 128 * 256; dst = W2t + (size_t)s * 256 * 128;
    }
    int li = threadIdx.x >> 5, lj = threadIdx.x & 31;
    #pragma unroll
    for (int i = 0; i < 4; ++i)
      t[li + i * 8][lj] = src[(size_t)(r0 + li + i * 8) * C + c0 + lj];
    __syncthreads();
    #pragma unroll
    for (int i = 0; i < 4; ++i)
      dst[(size_t)(c0 + li + i * 8) * R + r0 + lj] = f2bf(t[lj][li + i * 8]);
    return;
  }
  // wfuse: 128 blocks, 8 per source (16 hh rows each)
  const int q  = bid - 1024;
  const int s  = q >> 3, hb = q & 7;
  const int t  = threadIdx.x;
  const int hh = hb * 16 + (t >> 4);
  const int kb = (t & 15) * 2;
  const float* w2r = W2 + ((size_t)s * H_N + hh) * D_N;
  const float* wc1 = Wc1 + (size_t)s * D_N * K_N;
  float a0 = 0.f, a1 = 0.f;
  for (int d = 0; d < D_N; ++d) {
    float wv = w2r[d];
    a0 = fmaf(wv, wc1[d * K_N + kb], a0);
    a1 = fmaf(wv, wc1[d * K_N + kb + 1], a1);
  }
  Wft[((size_t)s * K_N + kb) * H_N + hh]     = f2bf(a0);
  Wft[((size_t)s * K_N + kb + 1) * H_N + hh] = f2bf(a1);
  if (hb == 0 && t < K_N) {
    float a = bc1[s * K_N + t];
    for (int d = 0; d < D_N; ++d)
      a = fmaf(b2[s * D_N + d], wc1[d * K_N + t], a);
    bcf[s * K_N + t] = a;
  }
}

// ---------------- fused main kernel ----------------
// grid = 256, block = 512 (8 waves), 1 block/CU (occupancy pinned by acc
// state — R6/R8). One barrier/source, double-buffered h (R9 schedule).
// NEW: GEMM1/GEMM2 use 32x32x16 MFMA — half the MFMA and ds_read instr
// count for the same FLOPs (R9 showed we're instr-count x latency bound).
//   GEMM1: wave w -> 32x32 tile (rt=w>>2 rows, ct=w&3 hcols), 16 MFMA.
//   GEMM2: wave w -> dcols [32w,32w+32), both rowtiles, 16 MFMA, B unique.
//   conf : waves 0-3, 16x16 path (unchanged).
// C layout (guide, HW-verified): col=lane&31, row=(reg&3)+8*(reg>>2)+4*(lane>>5).
__global__ __launch_bounds__(512, 2)
void lsi_main(const float* __restrict__ x,
              const float* __restrict__ b1,
              const float* __restrict__ b2,
              const float* __restrict__ Wc2,
              const float* __restrict__ bc2,
              const float* __restrict__ lam,
              const unsigned short* __restrict__ W1t,
              const unsigned short* __restrict__ W2t,
              const unsigned short* __restrict__ Wft,
              const float* __restrict__ bcf,
              float* __restrict__ out)
{
  __shared__ unsigned short x_lds[BT * D_N];      // 32 KB, swizzled
  __shared__ unsigned short h_lds[2][BT * H_N];   // 2 x 16 KB, swizzled
  __shared__ float cw_lds[2][BT];
  __shared__ float wsum_lds[BT];

  const int tid = threadIdx.x;
  const int w   = tid >> 6;       // wave 0..7
  const int l   = tid & 63;       // lane
  const int l31 = l & 31;
  const int hi  = l >> 5;         // 0/1 half-wave
  const int rA  = l & 15;
  const int g   = l >> 4;         // 0..3 (16x16 path)
  const int k8  = g * 8;
  const int b0  = blockIdx.x * BT;

  // ---- stage x tile into LDS as bf16 (swizzled) ----
  {
    int row = tid >> 3;                 // 0..63
    int c0  = (tid & 7) * 32;           // 8 threads per row
    const float* xr = x + (size_t)(b0 + row) * D_N + c0;
    #pragma unroll
    for (int cc = 0; cc < 4; ++cc) {
      float4 f0 = *(const float4*)(xr + cc * 8);
      float4 f1 = *(const float4*)(xr + cc * 8 + 4);
      bf16x8 u;
      u[0] = f2bf(f0.x); u[1] = f2bf(f0.y); u[2] = f2bf(f0.z); u[3] = f2bf(f0.w);
      u[4] = f2bf(f1.x); u[5] = f2bf(f1.y); u[6] = f2bf(f1.z); u[7] = f2bf(f1.w);
      unsigned off = (unsigned)(row * 512 + (c0 + cc * 8) * 2) ^ SWZ(row);
      *(bf16x8*)((char*)x_lds + off) = u;
    }
  }
  if (tid < BT) wsum_lds[tid] = 0.f;

  f32x16 out_acc[2];   // [rt] persistent (wave dcols 32w..32w+32)
  f32x16 acc2[2];      // [rt] outs(s), folded one source later
  #pragma unroll
  for (int i = 0; i < 16; ++i) { out_acc[0][i] = 0.f; out_acc[1][i] = 0.f; }

  // GEMM1(s) -> h buffer: wave w -> rows 32*(w>>2), hcols 32*(w&3)
  auto do_gemm1 = [&](int s, unsigned short* hw) {
    const int rt1 = w >> 2, ct1 = w & 3;
    const int arow = rt1 * 32 + l31;
    const int hcol = ct1 * 32 + l31;
    f32x16 acc1;
    #pragma unroll
    for (int i = 0; i < 16; ++i) acc1[i] = 0.f;
    const unsigned short* B1 = W1t + ((size_t)s * H_N + hcol) * D_N + hi * 8;
    #pragma unroll
    for (int kf = 0; kf < 16; ++kf) {
      bf16x8 bfr = *(const bf16x8*)(B1 + kf * 16);
      unsigned off = (unsigned)(arow * 512 + kf * 32 + hi * 16) ^ SWZ(arow);
      bf16x8 afr = *(const bf16x8*)((const char*)x_lds + off);
      acc1 = MFMA32(afr, bfr, acc1);
    }
    const float b1v = b1[s * H_N + hcol];   // lane-constant across regs
    #pragma unroll
    for (int r = 0; r < 16; ++r) {
      int row = rt1 * 32 + (r & 3) + 8 * (r >> 2) + 4 * hi;
      float v = fmaxf(acc1[r] + b1v, 0.f);
      unsigned off = (unsigned)(row * 256 + hcol * 2) ^ SWZ(row);
      *(unsigned short*)((char*)hw + off) = f2bf(v);
    }
  };

  __syncthreads();             // x staged
  do_gemm1(0, h_lds[0]);       // prologue
  __syncthreads();             // h(0) ready

  for (int s = 0; s < S_N; ++s) {
    const unsigned short* hr = (const unsigned short*)h_lds[s & 1];

    // ---- fold(s-1): VALU ----
    if (s > 0) {
      #pragma unroll
      for (int rt = 0; rt < 2; ++rt)
        #pragma unroll
        for (int q = 0; q < 4; ++q) {
          f32x4 c4 = *(const f32x4*)&cw_lds[(s + 1) & 1][rt * 32 + q * 8 + hi * 4];
          #pragma unroll
          for (int i = 0; i < 4; ++i)
            out_acc[rt][q * 4 + i] += c4[i] * acc2[rt][q * 4 + i];
        }
    }

    // ---- conf(s): waves 0-3 only; 16x16 path; wave w -> rows [16w,16w+16) ----
    if (w < 4) {
      f32x4 acc3[2];
      acc3[0] = (f32x4){0.f, 0.f, 0.f, 0.f};
      acc3[1] = (f32x4){0.f, 0.f, 0.f, 0.f};
      const unsigned short* Bf = Wft + ((size_t)s * K_N + rA) * H_N + k8;
      #pragma unroll
      for (int ks = 0; ks < 4; ++ks) {
        int row = w * 16 + rA;
        unsigned off = (unsigned)(row * 256 + (ks * 32 + k8) * 2) ^ SWZ(row);
        bf16x8 afr = *(const bf16x8*)((const char*)hr + off);
        acc3[0] = MFMA16(afr, *(const bf16x8*)(Bf + ks * 32), acc3[0]);
        acc3[1] = MFMA16(afr, *(const bf16x8*)(Bf + 16 * H_N + ks * 32), acc3[1]);
      }
      const float bcf0 = bcf[s * K_N + rA],  bcf1 = bcf[s * K_N + 16 + rA];
      const float wc20 = Wc2[s * K_N + rA],  wc21 = Wc2[s * K_N + 16 + rA];
      float pz[4];
      #pragma unroll
      for (int i = 0; i < 4; ++i)
        pz[i] = fmaxf(acc3[0][i] + bcf0, 0.f) * wc20 +
                fmaxf(acc3[1][i] + bcf1, 0.f) * wc21;
      #pragma unroll
      for (int m = 1; m < 16; m <<= 1)
        #pragma unroll
        for (int i = 0; i < 4; ++i)
          pz[i] += __shfl_xor(pz[i], m);
      if (rA == 0) {
        const float lam_s = lam[s], bc2_s = bc2[s];
        #pragma unroll
        for (int i = 0; i < 4; ++i) {
          float cv = lam_s / (1.f + __expf(-(pz[i] + bc2_s)));
          cw_lds[s & 1][w * 16 + g * 4 + i] = cv;
          wsum_lds[w * 16 + g * 4 + i] += cv;
        }
      }
    }

    // ---- GEMM2(s) -> acc2: wave w -> dcols [32w,32w+32), both rowtiles ----
    #pragma unroll
    for (int i = 0; i < 16; ++i) { acc2[0][i] = 0.f; acc2[1][i] = 0.f; }
    {
      const int dcol = w * 32 + l31;
      const unsigned short* B2 = W2t + ((size_t)s * D_N + dcol) * H_N + hi * 8;
      #pragma unroll
      for (int kf = 0; kf < 8; ++kf) {
        bf16x8 bfr = *(const bf16x8*)(B2 + kf * 16);
        #pragma unroll
        for (int rt = 0; rt < 2; ++rt) {
          int arow = rt * 32 + l31;
          unsigned off = (unsigned)(arow * 256 + kf * 32 + hi * 16) ^ SWZ(arow);
          bf16x8 afr = *(const bf16x8*)((const char*)hr + off);
          acc2[rt] = MFMA32(afr, bfr, acc2[rt]);
        }
      }
      const float b2v = b2[s * D_N + dcol];   // lane-constant
      #pragma unroll
      for (int rt = 0; rt < 2; ++rt)
        #pragma unroll
        for (int r = 0; r < 16; ++r)
          acc2[rt][r] += b2v;
    }

    // ---- GEMM1(s+1) -> other h buffer ----
    if (s + 1 < S_N) do_gemm1(s + 1, h_lds[(s + 1) & 1]);

    __syncthreads();   // single barrier per source
  }

  // ---------- epilogue: fold s=15, normalize, store ----------
  #pragma unroll
  for (int rt = 0; rt < 2; ++rt)
    #pragma unroll
    for (int q = 0; q < 4; ++q) {
      f32x4 c4 = *(const f32x4*)&cw_lds[(S_N - 1) & 1][rt * 32 + q * 8 + hi * 4];
      #pragma unroll
      for (int i = 0; i < 4; ++i)
        out_acc[rt][q * 4 + i] += c4[i] * acc2[rt][q * 4 + i];
    }
  {
    const int dcol = w * 32 + l31;
    #pragma unroll
    for (int rt = 0; rt < 2; ++rt)
      #pragma unroll
      for (int q = 0; q < 4; ++q) {
        f32x4 w4 = *(const f32x4*)&wsum_lds[rt * 32 + q * 8 + hi * 4];
        #pragma unroll
        for (int i = 0; i < 4; ++i) {
          int row = rt * 32 + q * 8 + hi * 4 + i;
          float winv = 1.f / (w4[i] + 1e-6f);
          out[(size_t)(b0 + row) * D_N + dcol] = out_acc[rt][q * 4 + i] * winv;
        }
      }
  }
}

extern "C" void kernel_launch(void* const* d_in, const int* in_sizes, int n_in,
                              void* d_out, int out_size, void* d_ws, size_t ws_size,
                              hipStream_t stream) {
  const float* x   = (const float*)d_in[0];
  const float* W1  = (const float*)d_in[1];
  const float* b1  = (const float*)d_in[2];
  const float* W2  = (const float*)d_in[3];
  const float* b2  = (const float*)d_in[4];
  const float* Wc1 = (const float*)d_in[5];
  const float* bc1 = (const float*)d_in[6];
  const float* Wc2 = (const float*)d_in[7];
  const float* bc2 = (const float*)d_in[8];
  const float* lam = (const float*)d_in[9];
  float* out = (float*)d_out;

  // ws: W1t 1MB | W2t 1MB | Wft 128KB | bcf 2KB
  unsigned short* W1t = (unsigned short*)d_ws;
  unsigned short* W2t = W1t + (size_t)S_N * H_N * D_N;
  unsigned short* Wft = W2t + (size_t)S_N * D_N * H_N;
  float* bcf = (float*)(Wft + (size_t)S_N * K_N * H_N);

  lsi_prep<<<dim3(1152), dim3(256), 0, stream>>>(W1, W2, Wc1, b2, bc1,
                                                 W1t, W2t, Wft, bcf);
  lsi_main<<<dim3(B_N / BT), dim3(512), 0, stream>>>(x, b1, b2, Wc2, bc2, lam,
                                                     W1t, W2t, Wft, bcf, out);
}